// Round 3
// baseline (290.172 us; speedup 1.0000x reference)
//
#include <hip/hip_runtime.h>
#include <math.h>

#define DELTA      0.04f
#define LOG_CLAMP  -100.0f
#define N          2048
#define PER_LANE   32              // N / 64
#define KI         8               // iterations of 4 elements per lane
#define ROWS_PER_BLOCK 4
#define BLOCK      256

// One WAVE per row. No LDS, no __syncthreads. Single streaming pass:
//   - anchors as 2x float4 per lane-iter (4 points), squared-dist argmin
//     with first-index tie-break (lane-strided indices ascend with k;
//     butterfly select prefers smaller index on ties)
//   - conf as float4 -> e = __expf(c) kept in 32 VGPRs, accumulate sum(e)
// Butterfly (shfl_xor) reductions: every lane converges to identical
// (dmin, imin, sume) -- bitwise deterministic.
// CE tail: sum log(1-p) via per-lane product of 32 factors + ONE __logf,
// then lane 0 patches the closest-index term and does the tiny gathers
// (L1/L2-hot: this wave just streamed that row).
__global__ __launch_bounds__(BLOCK) void row_kernel(
    const float* __restrict__ anchors,   // B x N x 2
    const float* __restrict__ offsets,   // B x N x 2
    const float* __restrict__ conf,      // B x N
    const float* __restrict__ gt,        // B x 2
    float* __restrict__ ce_part,         // B
    float* __restrict__ hu_part)         // B
{
    const int wid  = threadIdx.x >> 6;
    const int lane = threadIdx.x & 63;
    const int b    = blockIdx.x * ROWS_PER_BLOCK + wid;

    const float4* __restrict__ arow4 = (const float4*)(anchors + (size_t)b * N * 2);
    const float4* __restrict__ crow4 = (const float4*)(conf + (size_t)b * N);
    const float2 g = ((const float2*)gt)[b];

    float e[PER_LANE];
    float dmin = INFINITY;
    int   imin = 0;
    float sume = 0.0f;

    #pragma unroll
    for (int k = 0; k < KI; ++k) {
        const int q  = k * 64 + lane;    // 4-element group index
        const int n0 = 4 * q;            // ascending per lane with k
        const float4 a0 = arow4[2 * q];
        const float4 a1 = arow4[2 * q + 1];
        const float4 c  = crow4[q];

        float dx, dy, d;
        dx = a0.x - g.x; dy = a0.y - g.y; d = dx * dx + dy * dy;
        if (d < dmin) { dmin = d; imin = n0; }
        dx = a0.z - g.x; dy = a0.w - g.y; d = dx * dx + dy * dy;
        if (d < dmin) { dmin = d; imin = n0 + 1; }
        dx = a1.x - g.x; dy = a1.y - g.y; d = dx * dx + dy * dy;
        if (d < dmin) { dmin = d; imin = n0 + 2; }
        dx = a1.z - g.x; dy = a1.w - g.y; d = dx * dx + dy * dy;
        if (d < dmin) { dmin = d; imin = n0 + 3; }

        const float e0 = __expf(c.x);
        const float e1 = __expf(c.y);
        const float e2 = __expf(c.z);
        const float e3 = __expf(c.w);
        e[4 * k]     = e0;
        e[4 * k + 1] = e1;
        e[4 * k + 2] = e2;
        e[4 * k + 3] = e3;
        sume += (e0 + e1) + (e2 + e3);
    }

    // butterfly: all lanes converge to identical (dmin, imin) and sume
    #pragma unroll
    for (int off = 1; off < 64; off <<= 1) {
        const float d2 = __shfl_xor(dmin, off, 64);
        const int   i2 = __shfl_xor(imin, off, 64);
        if (d2 < dmin || (d2 == dmin && i2 < imin)) { dmin = d2; imin = i2; }
        sume += __shfl_xor(sume, off, 64);
    }

    const float inv = 1.0f / sume;

    float prod = 1.0f;
    #pragma unroll
    for (int i = 0; i < PER_LANE; ++i)
        prod *= fmaf(-e[i], inv, 1.0f);           // (1 - p_i)
    float slog = __logf(fmaxf(prod, 1e-37f));     // underflow guard; unreachable here
    #pragma unroll
    for (int off = 1; off < 64; off <<= 1)
        slog += __shfl_xor(slog, off, 64);

    if (lane == 0) {
        const int ci = imin;
        const float cci  = (conf + (size_t)b * N)[ci];
        const float p_ci = __expf(cci) * inv;
        const float logp = fmaxf(__logf(p_ci),        LOG_CLAMP);
        const float l1mp = fmaxf(__logf(1.0f - p_ci), LOG_CLAMP);
        const float ce = -(logp + (slog - l1mp));

        const float2 ca = ((const float2*)(anchors + (size_t)b * N * 2))[ci];
        const float2 co = ((const float2*)(offsets + (size_t)b * N * 2))[ci];
        const float x0 = co.x - (g.x - ca.x);
        const float x1 = co.y - (g.y - ca.y);
        const float a0 = fabsf(x0);
        const float a1 = fabsf(x1);
        const float h0 = (a0 <= DELTA) ? 0.5f * x0 * x0 : DELTA * (a0 - 0.5f * DELTA);
        const float h1 = (a1 <= DELTA) ? 0.5f * x1 * x1 : DELTA * (a1 - 0.5f * DELTA);

        ce_part[b] = ce;
        hu_part[b] = h0 + h1;
    }
}

// Single-block deterministic final reduce (double accumulate), 1024 threads.
__global__ __launch_bounds__(1024) void reduce_kernel(
    const float* __restrict__ ce_part,
    const float* __restrict__ hu_part,
    float* __restrict__ out, int nrows)
{
    double ce = 0.0, hu = 0.0;
    for (int i = threadIdx.x; i < nrows; i += 1024) {
        ce += (double)ce_part[i];
        hu += (double)hu_part[i];
    }
    #pragma unroll
    for (int off = 32; off > 0; off >>= 1) {
        ce += __shfl_down(ce, off, 64);
        hu += __shfl_down(hu, off, 64);
    }
    __shared__ double sc[16], sh[16];
    const int wid = threadIdx.x >> 6, lane = threadIdx.x & 63;
    if (lane == 0) { sc[wid] = ce; sh[wid] = hu; }
    __syncthreads();
    if (threadIdx.x == 0) {
        double tce = 0.0, thu = 0.0;
        #pragma unroll
        for (int w = 0; w < 16; ++w) { tce += sc[w]; thu += sh[w]; }
        out[0] = (float)(tce + thu);
        out[1] = (float)tce;
        out[2] = (float)thu;
    }
}

extern "C" void kernel_launch(void* const* d_in, const int* in_sizes, int n_in,
                              void* d_out, int out_size, void* d_ws, size_t ws_size,
                              hipStream_t stream) {
    const float* anchors = (const float*)d_in[0];
    const float* offsets = (const float*)d_in[1];
    const float* conf    = (const float*)d_in[2];
    const float* gt      = (const float*)d_in[3];
    float* out = (float*)d_out;

    const int B = in_sizes[3] / 2;   // ground_truth is (B, 2)

    float* ce_part = (float*)d_ws;       // B floats
    float* hu_part = ce_part + B;        // B floats

    row_kernel<<<B / ROWS_PER_BLOCK, BLOCK, 0, stream>>>(anchors, offsets, conf, gt,
                                                         ce_part, hu_part);
    reduce_kernel<<<1, 1024, 0, stream>>>(ce_part, hu_part, out, B);
}